// Round 7
// baseline (296.005 us; speedup 1.0000x reference)
//
#include <hip/hip_runtime.h>
#include <hip/hip_fp16.h>

// Shapes (fixed by the problem)
#define LL 192
#define FF 2048

typedef __attribute__((__ext_vector_type__(8)))  __bf16 bf16x8;
typedef __attribute__((__ext_vector_type__(4)))  __bf16 bf16x4;
typedef __attribute__((__ext_vector_type__(4)))  float  f32x4;
typedef __attribute__((__ext_vector_type__(2)))  _Float16 f16x2;

#define MFMA16(a, b, c) __builtin_amdgcn_mfma_f32_16x16x32_bf16((a), (b), (c), 0, 0, 0)

// Empirical gfx950 laws (R1-R16 evidence):
//  - OCCUPANCY CLIFF AT 128 VGPR (m69): keep budget <=128 via
//    __launch_bounds__(256,2). Confirmed R14/R15 (104-108 VGPR, ~20% occ).
//  - R15 audit: removing ALL staging barriers changed nothing (114us).
//    Invariant across R10/R14/R15: MfmaUtil+VALUBusy ~= 63% -> in-wave
//    PHASE SERIALIZATION ([MFMA burst][VALU burst] alternation; pipes
//    idle in antiphase). Per-SIMD busy: 77k cyc MFMA + 96k VALU of 274k.
//  - R16 fix: 16-row software pipeline (two 12-reg acc sets) so the
//    epilogue of tile n overlaps the matrix-pipe drain of tile n+1;
//    1 q per block (Bf 96->48 regs) keeps footprint under the cliff.
//  - A-frags are wave-invariant and L2-resident: load direct from global
//    (R15 proved FETCH flat). sched_barrier(0) pins the interleave.
//  - R11 win kept: packed-f16 DPP quad reduce + pk_mul epilogue.

// DPP control must be a compile-time constant -> template parameter.
template<int CTL>
__device__ __forceinline__ unsigned dppu(unsigned x) {
    return (unsigned)__builtin_amdgcn_mov_dpp((int)x, CTL, 0xF, 0xF, true);
}
__device__ __forceinline__ unsigned pkrtz_u(float a, float b) {
    return __builtin_bit_cast(unsigned, __builtin_amdgcn_cvt_pkrtz(a, b));
}
__device__ __forceinline__ unsigned hmax2u(unsigned a, unsigned b) {
    unsigned r;
    asm("v_pk_max_f16 %0, %1, %2" : "=v"(r) : "v"(a), "v"(b));
    return r;
}

// ---------------------------------------------------------------------------
// Kernel 1: fused projection + prep (unchanged from R10).
// ---------------------------------------------------------------------------
__launch_bounds__(256, 2)
__global__ void proj_prep_kernel(const float* __restrict__ qf_in,
                                 const float* __restrict__ gf_in,
                                 const float* __restrict__ fc0w,
                                 const float* __restrict__ fc0b,
                                 const float* __restrict__ se,
                                 const float* __restrict__ fc2w,
                                 const float* __restrict__ fc2b,
                                 const float* __restrict__ bn2g,
                                 const float* __restrict__ bn2b,
                                 const float* __restrict__ fc3w,
                                 __bf16* __restrict__ kfragA,
                                 __bf16* __restrict__ qfrag16,
                                 float* __restrict__ sig32,
                                 __bf16* __restrict__ fc2w_bf,
                                 float* __restrict__ h2,
                                 float* __restrict__ bb2,
                                 float* __restrict__ f3)
{
    int bx = blockIdx.x, tid = threadIdx.x;
    if (bx >= 1152) {
        int i0 = (bx - 1152) * 256 + tid;
        const int stride = 160 * 256;
        const float c1 = rsqrtf(1.f + 1e-5f);
        for (int i = i0; i < LL * LL; i += stride) {
            int r = i & 3, lane = (i >> 2) & 63, tile = i >> 8;
            int jt = tile % 12, st = tile / 12;
            int s = st * 16 + (lane >> 4) * 4 + r;
            int t = jt * 16 + (lane & 15);
            sig32[i] = 1.f / (1.f + __expf(-se[s * 192 + t]));
        }
        for (int i = i0; i < FF * LL; i += stride)
            fc2w_bf[i] = (__bf16)fc2w[i];
        for (int i = i0; i < FF; i += stride) {
            float h = bn2g[i] * c1;
            h2[i]  = h;
            bb2[i] = fc2b[i] * h + bn2b[i];
            f3[i]  = fc3w[i];
        }
        return;
    }
    __shared__ __bf16 Xs[32][136];
    __shared__ __bf16 Ws[128][136];
    __shared__ __bf16 Os[4096];
    const float* src = (bx < 384) ? (qf_in + (size_t)bx * (32 * 128))
                                  : (gf_in + (size_t)(bx - 384) * (32 * 128));
#pragma unroll
    for (int it = 0; it < 4; ++it) {
        int e = (it * 256 + tid) * 4;
        int r = e >> 7, c = e & 127;
        float4 v = *reinterpret_cast<const float4*>(src + e);
        bf16x4 xv;
        xv[0] = (__bf16)v.x; xv[1] = (__bf16)v.y;
        xv[2] = (__bf16)v.z; xv[3] = (__bf16)v.w;
        *reinterpret_cast<bf16x4*>(&Xs[r][c]) = xv;
    }
#pragma unroll
    for (int it = 0; it < 16; ++it) {
        int e = (it * 256 + tid) * 4;
        int r = e >> 7, c = e & 127;
        float4 v = *reinterpret_cast<const float4*>(fc0w + e);
        bf16x4 xv;
        xv[0] = (__bf16)v.x; xv[1] = (__bf16)v.y;
        xv[2] = (__bf16)v.z; xv[3] = (__bf16)v.w;
        *reinterpret_cast<bf16x4*>(&Ws[r][c]) = xv;
    }
    __syncthreads();

    int wv = tid >> 6, lane = tid & 63, quad = lane >> 4, l16 = lane & 15;
    int n0 = wv * 32;
    f32x4 acc[2][2];
#pragma unroll
    for (int m = 0; m < 2; ++m)
#pragma unroll
        for (int n = 0; n < 2; ++n) acc[m][n] = (f32x4){0.f, 0.f, 0.f, 0.f};
#pragma unroll
    for (int ks = 0; ks < 4; ++ks) {
        bf16x8 a0 = *reinterpret_cast<const bf16x8*>(&Xs[l16][ks * 32 + quad * 8]);
        bf16x8 a1 = *reinterpret_cast<const bf16x8*>(&Xs[16 + l16][ks * 32 + quad * 8]);
        bf16x8 b0 = *reinterpret_cast<const bf16x8*>(&Ws[n0 + l16][ks * 32 + quad * 8]);
        bf16x8 b1 = *reinterpret_cast<const bf16x8*>(&Ws[n0 + 16 + l16][ks * 32 + quad * 8]);
        acc[0][0] = MFMA16(a0, b0, acc[0][0]);
        acc[0][1] = MFMA16(a0, b1, acc[0][1]);
        acc[1][0] = MFMA16(a1, b0, acc[1][0]);
        acc[1][1] = MFMA16(a1, b1, acc[1][1]);
    }
#pragma unroll
    for (int mt = 0; mt < 2; ++mt)
#pragma unroll
        for (int nt = 0; nt < 2; ++nt) {
            int d = n0 + nt * 16 + l16;
            float bv = fc0b[d];
            int abase = mt * 2048 + (d >> 5) * 512 + ((d >> 3) & 3) * 128 + (d & 7);
#pragma unroll
            for (int r = 0; r < 4; ++r)
                Os[abase + (quad * 4 + r) * 8] = (__bf16)(acc[mt][nt][r] + bv);
        }
    __syncthreads();

    int row0 = bx * 32;
    __bf16* dst;
    if (bx < 384) {
        int qi = row0 / 192, tg0 = (row0 % 192) >> 4;
        dst = qfrag16 + qi * 24576 + tg0 * 2048;
    } else {
        int rk0 = row0 - 12288;
        int ki = rk0 / 192, sg0 = (rk0 % 192) >> 4;
        dst = kfragA + ki * 24576 + sg0 * 2048;
    }
#pragma unroll
    for (int it = 0; it < 2; ++it) {
        int e = (it * 256 + tid) * 8;
        *reinterpret_cast<bf16x8*>(dst + e) =
            *reinterpret_cast<const bf16x8*>(&Os[e]);
    }
}

// ---------------------------------------------------------------------------
// score_kernel helpers (R16): 16-row tile primitives, all statically
// indexed after unroll.
// ---------------------------------------------------------------------------
__device__ __forceinline__ void load_a(bf16x8 (&a)[4], const __bf16* ka, int t) {
#pragma unroll
    for (int ks = 0; ks < 4; ++ks)
        a[ks] = *reinterpret_cast<const bf16x8*>(ka + t * 2048 + ks * 512);
}

__device__ __forceinline__ void load_sig(f32x4 (&s)[3], const float* sigb, int st) {
    const float* sp = sigb + st * 3072;
    s[0] = *reinterpret_cast<const f32x4*>(sp);
    s[1] = *reinterpret_cast<const f32x4*>(sp + 256);
    s[2] = *reinterpret_cast<const f32x4*>(sp + 512);
}

__device__ __forceinline__ void mfma_tile(f32x4 (&acc)[3], const bf16x8 (&a)[4],
                                          const bf16x8 (&Bf)[3][4]) {
    const f32x4 Z4 = (f32x4){0.f, 0.f, 0.f, 0.f};
#pragma unroll
    for (int j = 0; j < 3; ++j) acc[j] = MFMA16(a[0], Bf[j][0], Z4);
#pragma unroll
    for (int ks = 1; ks < 4; ++ks)
#pragma unroll
        for (int j = 0; j < 3; ++j) acc[j] = MFMA16(a[ks], Bf[j][ks], acc[j]);
}

__device__ __forceinline__ void epi_tile(const f32x4 (&acc)[3], const f32x4 (&s)[3],
                                         float (&cm)[3], int st,
                                         int quad, int l16, int w,
                                         unsigned (*rowP)[98]) {
    f32x4 v0 = acc[0] * s[0];
    f32x4 v1 = acc[1] * s[1];
    f32x4 v2 = acc[2] * s[2];
    // col maxes over r folded into running cm (v_max3)
    cm[0] = fmaxf(fmaxf(cm[0], fmaxf(v0[0], v0[1])), fmaxf(v0[2], v0[3]));
    cm[1] = fmaxf(fmaxf(cm[1], fmaxf(v1[0], v1[1])), fmaxf(v1[2], v1[3]));
    cm[2] = fmaxf(fmaxf(cm[2], fmaxf(v2[0], v2[1])), fmaxf(v2[2], v2[3]));
    // row maxes over j, packed f16 pairs (RTZ monotone: max(rtz)=rtz(max))
    unsigned h01 = pkrtz_u(fmaxf(fmaxf(v0[0], v1[0]), v2[0]),
                           fmaxf(fmaxf(v0[1], v1[1]), v2[1]));
    unsigned h23 = pkrtz_u(fmaxf(fmaxf(v0[2], v1[2]), v2[2]),
                           fmaxf(fmaxf(v0[3], v1[3]), v2[3]));
    // quad reduce over l16 bits 0,1: DPP + v_pk_max_f16
    h01 = hmax2u(h01, dppu<0xB1>(h01));
    h01 = hmax2u(h01, dppu<0x4E>(h01));
    h23 = hmax2u(h23, dppu<0xB1>(h23));
    h23 = hmax2u(h23, dppu<0x4E>(h23));
    if ((l16 & 3) == 0) {
        int rp = st * 8 + quad * 2;
        rowP[(l16 >> 2) * 4 + w][rp]     = h01;
        rowP[(l16 >> 2) * 4 + w][rp + 1] = h23;
    }
}

// ---------------------------------------------------------------------------
// Kernel 2: score GEMM + sigmoid-modulation + dual max-reduce (R16).
//    Grid 2048: block owns 1 q x 4 keys.  256 threads = 4 waves, wave w
//    owns fixed t-slice {3w..3w+2}:
//      - Bf (query) frags: 3x4 = 48 VGPRs (halved vs 2-q blocking)
//      - A direct from global (wave-invariant, L2-resident; R15-proven)
//      - 16-row tile SOFTWARE PIPELINE: two acc sets (12 regs each);
//        per half-body: sig(st) -> MFMA(st+1) -> a-load(st+3) ->
//        sched_barrier(0) -> epilogue(st).  Epilogue VALU overlaps the
//        matrix-pipe drain of the next tile IN-WAVE (no occupancy bet).
//      - packed-f16 DPP quad reduce + pk_mul epilogue (R11, proven)
//      - __launch_bounds__(256,2): HARD 128-VGPR cap.
//    LDS 6,272 B (rowP only); 2 barriers per key (combine fence).
// ---------------------------------------------------------------------------
__launch_bounds__(256, 2)
__global__ void score_kernel(const __bf16* __restrict__ kfragA,
                             const __bf16* __restrict__ qfrag16,
                             const float* __restrict__ sig32,
                             const float* __restrict__ bn1g,
                             const float* __restrict__ bn1b,
                             __bf16* __restrict__ Sred)
{
    __shared__ unsigned rowP[16][98];      // 6,272 B: f16x2 row-pair partials

    int tid = threadIdx.x;
    int q0 = blockIdx.x & 63;
    int kbase = (blockIdx.x >> 6) << 2;    // 32 k-groups of 4 keys
    int w = tid >> 6, lane = tid & 63, quad = lane >> 4, l16 = lane & 15;
    const float g1c = bn1g[0] * rsqrtf(1.f + 1e-5f);
    const float b1v = bn1b[0];
    // per-thread sig base: ((st*12+3w)*64+lane)*4 = st*3072 + 768w + 4*lane
    const float* sigb = sig32 + 768 * w + 4 * lane;

    // Hoist B (query) fragments: 3 x 4 = 48 VGPRs
    bf16x8 Bf[3][4];
    {
        const __bf16* qb = qfrag16 + (size_t)q0 * 24576 + lane * 8;
#pragma unroll
        for (int j = 0; j < 3; ++j)
#pragma unroll
            for (int ks = 0; ks < 4; ++ks)
                Bf[j][ks] = *reinterpret_cast<const bf16x8*>(
                    qb + ((3 * w + j) * 4 + ks) * 512);
    }

#pragma unroll 1
    for (int kk = 0; kk < 4; ++kk) {
        int kidx = kbase + kk;
        const __bf16* ka = kfragA + (size_t)kidx * 24576 + lane * 8;
        float cm[3] = {-3.0e38f, -3.0e38f, -3.0e38f};

        bf16x8 aA[4], aB[4];
        f32x4 accA[3], accB[3];
        f32x4 sv[3];

        // pipeline prologue: tiles 0,1 in flight; tile0 computed
        load_a(aA, ka, 0);
        load_a(aB, ka, 1);
        mfma_tile(accA, aA, Bf);
        load_a(aA, ka, 2);

#pragma unroll
        for (int st = 0; st < 10; st += 2) {
            // half A: compute tile st+1, retire tile st
            load_sig(sv, sigb, st);
            mfma_tile(accB, aB, Bf);
            load_a(aB, ka, st + 3);
            __builtin_amdgcn_sched_barrier(0);
            epi_tile(accA, sv, cm, st, quad, l16, w, rowP);

            // half B: compute tile st+2, retire tile st+1
            load_sig(sv, sigb, st + 1);
            mfma_tile(accA, aA, Bf);
            load_a(aA, ka, (st + 4 > 11) ? 11 : st + 4);
            __builtin_amdgcn_sched_barrier(0);
            epi_tile(accB, sv, cm, st + 1, quad, l16, w, rowP);
        }
        // drain: tile 11 compute, retire 10 and 11
        load_sig(sv, sigb, 10);
        mfma_tile(accB, aB, Bf);
        __builtin_amdgcn_sched_barrier(0);
        epi_tile(accA, sv, cm, 10, quad, l16, w, rowP);
        load_sig(sv, sigb, 11);
        epi_tile(accB, sv, cm, 11, quad, l16, w, rowP);

        // col-max (max over s, indexed by t): reduce over quad, direct write
        {
            size_t ob = (size_t)(q0 * 128 + kidx) * 384;
            float v0 = cm[0], v1 = cm[1], v2 = cm[2];
            v0 = fmaxf(v0, __shfl_xor(v0, 16, 64));
            v0 = fmaxf(v0, __shfl_xor(v0, 32, 64));
            v1 = fmaxf(v1, __shfl_xor(v1, 16, 64));
            v1 = fmaxf(v1, __shfl_xor(v1, 32, 64));
            v2 = fmaxf(v2, __shfl_xor(v2, 16, 64));
            v2 = fmaxf(v2, __shfl_xor(v2, 32, 64));
            if (quad == 0) {
                Sred[ob + (3 * w + 0) * 16 + l16] = (__bf16)(v0 * g1c + b1v);
                Sred[ob + (3 * w + 1) * 16 + l16] = (__bf16)(v1 * g1c + b1v);
                Sred[ob + (3 * w + 2) * 16 + l16] = (__bf16)(v2 * g1c + b1v);
            }
        }

        __syncthreads();   // all waves' rowP writes for this key visible

        // row-max combine (max over t, indexed by s)
        if (tid < 96) {
            size_t ob = (size_t)(q0 * 128 + kidx) * 384;
            unsigned m = rowP[0][tid];
#pragma unroll
            for (int c = 1; c < 16; ++c)
                m = hmax2u(m, rowP[c][tid]);
            __half2 hm = __builtin_bit_cast(__half2, m);
            float lo = __low2float(hm), hi = __high2float(hm);
            unsigned two =
                (unsigned)__builtin_bit_cast(unsigned short,
                    (__bf16)(lo * g1c + b1v)) |
                ((unsigned)__builtin_bit_cast(unsigned short,
                    (__bf16)(hi * g1c + b1v)) << 16);
            *reinterpret_cast<unsigned*>(&Sred[ob + 192 + 2 * tid]) = two;
        }

        __syncthreads();   // combine done before next key's rowP writes
    }
}

// ---------------------------------------------------------------------------
// Kernel 3: fused fc2 + bn2 + relu + fc3 + pair-sum + bn3 (unchanged).
// ---------------------------------------------------------------------------
__launch_bounds__(512, 1)
__global__ void mlp_kernel(const __bf16* __restrict__ Sred,
                           const __bf16* __restrict__ fc2w_bf,
                           const float* __restrict__ h2,
                           const float* __restrict__ bb2,
                           const float* __restrict__ f3,
                           const float* __restrict__ fc3b,
                           const float* __restrict__ bn3g,
                           const float* __restrict__ bn3b,
                           float* __restrict__ out)
{
    __shared__ __bf16 As[64][200];
    __shared__ float  psum_lds[8][64];
    int bx = blockIdx.x, tid = threadIdx.x;
    const __bf16* asrc = Sred + (size_t)bx * (64 * 192);
#pragma unroll
    for (int it = 0; it < 3; ++it) {
        int e = (it * 512 + tid) * 8;
        int r = e / 192, c = e - r * 192;
        *reinterpret_cast<bf16x8*>(&As[r][c]) =
            *reinterpret_cast<const bf16x8*>(asrc + e);
    }
    __syncthreads();

    int wv = tid >> 6, lane = tid & 63, quad = lane >> 4, l16 = lane & 15;
    bf16x8 af[4][6];
#pragma unroll
    for (int m = 0; m < 4; ++m)
#pragma unroll
        for (int kk = 0; kk < 6; ++kk)
            af[m][kk] = *reinterpret_cast<const bf16x8*>(
                &As[m * 16 + l16][kk * 32 + quad * 8]);

    float ps[4][4] = {{0.f,0.f,0.f,0.f},{0.f,0.f,0.f,0.f},
                      {0.f,0.f,0.f,0.f},{0.f,0.f,0.f,0.f}};
    for (int nt = 0; nt < 16; ++nt) {
        int n0 = wv * 256 + nt * 16;
        f32x4 acc[4];
#pragma unroll
        for (int m = 0; m < 4; ++m) acc[m] = (f32x4){0.f, 0.f, 0.f, 0.f};
        const __bf16* bp = fc2w_bf + (size_t)(n0 + l16) * 192 + quad * 8;
#pragma unroll
        for (int kk = 0; kk < 6; ++kk) {
            bf16x8 b = *reinterpret_cast<const bf16x8*>(bp + kk * 32);
#pragma unroll
            for (int m = 0; m < 4; ++m) acc[m] = MFMA16(af[m][kk], b, acc[m]);
        }
        int n = n0 + l16;
        float hh = h2[n], bb = bb2[n], ffv = f3[n];
#pragma unroll
        for (int m = 0; m < 4; ++m)
#pragma unroll
            for (int r = 0; r < 4; ++r)
                ps[m][r] += fmaxf(acc[m][r] * hh + bb, 0.f) * ffv;
    }
#pragma unroll
    for (int m = 0; m < 4; ++m)
#pragma unroll
        for (int r = 0; r < 4; ++r) {
            float v = ps[m][r];
            v += __shfl_xor(v, 1, 64);
            v += __shfl_xor(v, 2, 64);
            v += __shfl_xor(v, 4, 64);
            v += __shfl_xor(v, 8, 64);
            if (l16 == 0) psum_lds[wv][m * 16 + quad * 4 + r] = v;
        }
    __syncthreads();
    if (tid < 32) {
        float s = 0.f;
#pragma unroll
        for (int w = 0; w < 8; ++w)
            s += psum_lds[w][2 * tid] + psum_lds[w][2 * tid + 1];
        const float c1 = rsqrtf(1.f + 1e-5f);
        out[bx * 32 + tid] = (s + 2.f * fc3b[0]) * (bn3g[0] * c1) + bn3b[0];
    }
}

// ---------------------------------------------------------------------------
extern "C" void kernel_launch(void* const* d_in, const int* in_sizes, int n_in,
                              void* d_out, int out_size, void* d_ws, size_t ws_size,
                              hipStream_t stream)
{
    const float* q_feat = (const float*)d_in[0];
    const float* g_feat = (const float*)d_in[1];
    const float* se     = (const float*)d_in[2];
    const float* fc0w   = (const float*)d_in[3];
    const float* fc0b   = (const float*)d_in[4];
    const float* fc2w   = (const float*)d_in[5];
    const float* fc2b   = (const float*)d_in[6];
    const float* fc3w   = (const float*)d_in[7];
    const float* fc3b   = (const float*)d_in[8];
    const float* bn1g   = (const float*)d_in[9];
    const float* bn1b   = (const float*)d_in[10];
    const float* bn2g   = (const float*)d_in[11];
    const float* bn2b   = (const float*)d_in[12];
    const float* bn3g   = (const float*)d_in[13];
    const float* bn3b   = (const float*)d_in[14];
    float* out = (float*)d_out;

    char* ws = (char*)d_ws;
    __bf16* kfragA   = (__bf16*)(ws);                 //  6,291,456 B
    __bf16* qfrag16  = (__bf16*)(ws +  6291456);      //  3,145,728 B
    float*  sig32    = (float*) (ws +  9437184);      //    147,456 B
    __bf16* fc2w_bf  = (__bf16*)(ws +  9584640);      //    786,432 B
    float*  h2       = (float*) (ws + 10371072);      //      8,192 B
    float*  bb2      = (float*) (ws + 10379264);      //      8,192 B
    float*  f3       = (float*) (ws + 10387456);      //      8,192 B
    __bf16* Sred     = (__bf16*)(ws + 10395648);      //  6,291,456 B (16.69 MB total)

    proj_prep_kernel<<<1312, 256, 0, stream>>>(q_feat, g_feat, fc0w, fc0b, se,
                                               fc2w, fc2b, bn2g, bn2b, fc3w,
                                               kfragA, qfrag16, sig32, fc2w_bf,
                                               h2, bb2, f3);
    score_kernel<<<2048, 256, 0, stream>>>(kfragA, qfrag16, sig32, bn1g, bn1b, Sred);
    mlp_kernel<<<256, 512, 0, stream>>>(Sred, fc2w_bf, h2, bb2, f3,
                                        fc3b, bn3g, bn3b, out);
}